// Round 2
// baseline (4454.618 us; speedup 1.0000x reference)
//
#include <hip/hip_runtime.h>

// LSTM: B=256, T=512, I=64, H=512, G=4H=2048.
// gates = W @ [h; x], W = [R | kernel^T], K = 576.
// Persistent kernel: 256 WGs = 16 batch-groups x 16 gate-slices; W in VGPRs,
// c in VGPRs, h exchanged per step through global memory with a group-scoped
// release/acquire counter barrier (16 WGs per group).
#define TSTEPS 512
#define BATCH  256
#define ISZ    64
#define HSZ    512
#define GSZ    2048
#define KCAT   576
#define NKT    18
#define MT     8
#define BG     16
#define HS     32

typedef __attribute__((ext_vector_type(8))) short short8;
typedef __attribute__((ext_vector_type(4))) float f32x4;

static __device__ __forceinline__ unsigned short f2bf(float f) {
    unsigned int u = __float_as_uint(f);
    return (unsigned short)((u + 0x7fffu + ((u >> 16) & 1u)) >> 16);  // RNE
}
static __device__ __forceinline__ float sig_(float x) {
    return 1.0f / (1.0f + __expf(-x));
}
static __device__ __forceinline__ float tanh_(float x) {
    float e = __expf(-2.0f * fabsf(x));
    float t = (1.0f - e) / (1.0f + e);
    return copysignf(t, x);
}

// Pack W = [R | kernel^T] (fp32) into bf16 MFMA A-fragment order (unchanged).
__global__ void pack_w(const float* __restrict__ R, const float* __restrict__ Kin,
                       unsigned short* __restrict__ wpack)
{
    const int t  = blockIdx.x * 256 + threadIdx.x;
    const int l  = t & 63;
    const int kt = (t >> 6) % NKT;
    const int m  = (t / (64 * NKT)) & 7;
    const int jj = t / (64 * NKT * MT);
    const int r   = 16 * m + (l & 15);
    const int q   = r & 3;
    const int hco = r >> 2;
    const int grow  = q * HSZ + jj * HS + hco;
    const int kbase = kt * 32 + (l >> 4) * 8;
    unsigned int pk[4];
#pragma unroll
    for (int p = 0; p < 4; ++p) {
        const int k0 = kbase + 2 * p;
        const int k1 = k0 + 1;
        const float f0 = (k0 < HSZ) ? R[(size_t)grow * HSZ + k0]
                                    : Kin[(size_t)(k0 - HSZ) * GSZ + grow];
        const float f1 = (k1 < HSZ) ? R[(size_t)grow * HSZ + k1]
                                    : Kin[(size_t)(k1 - HSZ) * GSZ + grow];
        pk[p] = (unsigned)f2bf(f0) | ((unsigned)f2bf(f1) << 16);
    }
    uint4 v = make_uint4(pk[0], pk[1], pk[2], pk[3]);
    *reinterpret_cast<uint4*>(wpack + (size_t)t * 8) = v;
}

__global__ void zero_cnt(int* __restrict__ cnt) {
    cnt[threadIdx.x] = 0;
}

__global__ __launch_bounds__(256, 2) void lstm_persist(
    const unsigned short* __restrict__ wpack,
    const float* __restrict__ input_seq,
    const float* __restrict__ bias,
    unsigned short* __restrict__ hbuf0,
    unsigned short* __restrict__ hbuf1,
    float* __restrict__ hlast,
    int* __restrict__ cnt)
{
    __shared__ unsigned short lds_B[16][584];   // [batch][k], +8 pad
    __shared__ unsigned short lds_hn[16][40];
    const int tid = threadIdx.x;
    const int bid = blockIdx.x;
    // XCD swizzle: 16 WGs of group gi share bid%8 -> same XCD (heuristic).
    const int gi = (bid & 7) + 8 * (bid >> 7);
    const int jj = (bid >> 3) & 15;

    const int w  = tid >> 6;
    const int l  = tid & 63;
    const int bb = l & 15;     // batch within group (D col)
    const int lg = l >> 4;
    const int m0 = 2 * w, m1 = 2 * w + 1;

    // ---- one-time: W fragments into registers (144 VGPRs) ----
    short8 wA[NKT], wB[NKT];
#pragma unroll
    for (int kt = 0; kt < NKT; ++kt) {
        wA[kt] = *reinterpret_cast<const short8*>(
            wpack + (((size_t)(jj * MT + m0) * NKT + kt) * 64 + l) * 8);
        wB[kt] = *reinterpret_cast<const short8*>(
            wpack + (((size_t)(jj * MT + m1) * NKT + kt) * 64 + l) * 8);
    }
    // bias into registers
    const int hc0 = 4 * m0 + lg, hc1 = 4 * m1 + lg;
    const int gh0 = jj * HS + hc0, gh1 = jj * HS + hc1;
    float bs0[4], bs1[4];
#pragma unroll
    for (int qg = 0; qg < 4; ++qg) {
        bs0[qg] = bias[qg * HSZ + gh0];
        bs1[qg] = bias[qg * HSZ + gh1];
    }

    float c0 = 0.f, c1 = 0.f;

    // x prefetch: thread (xb, xck) owns 4 floats of batch xb's x_t
    const int xb = tid >> 4, xck = tid & 15;
    const float* xbase = input_seq + (size_t)(gi * BG + xb) * (TSTEPS * ISZ) + xck * 4;
    float4 xr = *reinterpret_cast<const float4*>(xbase);
    int* const mycnt = cnt + gi * 16;

    for (int s = 0; s < TSTEPS; ++s) {
        // ---- wait for h(s) from the 15 peer WGs ----
        if (s > 0 && tid == 0) {
            while (__hip_atomic_load(mycnt, __ATOMIC_ACQUIRE,
                                     __HIP_MEMORY_SCOPE_AGENT) < 16 * s)
                __builtin_amdgcn_s_sleep(2);
        }
        __syncthreads();   // A: spin done; prev MFMA reads done (via sync C)

        // stage x(s)
        uint2 px;
        px.x = (unsigned)f2bf(xr.x) | ((unsigned)f2bf(xr.y) << 16);
        px.y = (unsigned)f2bf(xr.z) | ((unsigned)f2bf(xr.w) << 16);
        *reinterpret_cast<uint2*>(&lds_B[xb][HSZ + xck * 4]) = px;
        if (s + 1 < TSTEPS)
            xr = *reinterpret_cast<const float4*>(xbase + (size_t)(s + 1) * ISZ);

        // stage h(s)
        if (s > 0) {
            const unsigned short* hr = (s & 1) ? hbuf1 : hbuf0;
            const uint4* src = reinterpret_cast<const uint4*>(
                hr + (size_t)(gi * BG + xb) * HSZ + xck * 32);
            uint4 a0 = src[0], a1 = src[1], a2 = src[2], a3 = src[3];
            uint4* dst = reinterpret_cast<uint4*>(&lds_B[xb][xck * 32]);
            dst[0] = a0; dst[1] = a1; dst[2] = a2; dst[3] = a3;
        } else {
            uint4 z = make_uint4(0, 0, 0, 0);
            uint4* dst = reinterpret_cast<uint4*>(&lds_B[xb][xck * 32]);
            dst[0] = z; dst[1] = z; dst[2] = z; dst[3] = z;
        }
        __syncthreads();   // B: staging complete

        f32x4 acc0 = {0.f, 0.f, 0.f, 0.f};
        f32x4 acc1 = {0.f, 0.f, 0.f, 0.f};
#pragma unroll
        for (int kt = 0; kt < NKT; ++kt) {
            const short8 bf = *reinterpret_cast<const short8*>(
                &lds_B[bb][kt * 32 + lg * 8]);
            acc0 = __builtin_amdgcn_mfma_f32_16x16x32_bf16(wA[kt], bf, acc0, 0, 0, 0);
            acc1 = __builtin_amdgcn_mfma_f32_16x16x32_bf16(wB[kt], bf, acc1, 0, 0, 0);
        }

        // ---- lane-local cell update (regs 0..3 = f,i,c',o of one (hc,bb)) ----
        {
            const float fg = sig_(acc0[0] + bs0[0]);
            const float ig = sig_(acc0[1] + bs0[1]);
            const float cp = tanh_(acc0[2] + bs0[2]);
            const float og = sig_(acc0[3] + bs0[3]);
            c0 = fg * c0 + ig * cp;
            const float h = og * tanh_(c0);
            lds_hn[bb][hc0] = f2bf(h);
            if (s == TSTEPS - 1)
                hlast[(size_t)(gi * BG + bb) * HSZ + gh0] = h;
        }
        {
            const float fg = sig_(acc1[0] + bs1[0]);
            const float ig = sig_(acc1[1] + bs1[1]);
            const float cp = tanh_(acc1[2] + bs1[2]);
            const float og = sig_(acc1[3] + bs1[3]);
            c1 = fg * c1 + ig * cp;
            const float h = og * tanh_(c1);
            lds_hn[bb][hc1] = f2bf(h);
            if (s == TSTEPS - 1)
                hlast[(size_t)(gi * BG + bb) * HSZ + gh1] = h;
        }
        __syncthreads();   // C: lds_hn ready; lds_B reads finished

        if (s < TSTEPS - 1) {
            if (tid < 64) {
                const int b = tid >> 2, c4 = tid & 3;
                uint4 v = *reinterpret_cast<const uint4*>(&lds_hn[b][c4 * 8]);
                unsigned short* hw = (s & 1) ? hbuf0 : hbuf1;  // parity of s+1
                *reinterpret_cast<uint4*>(
                    hw + (size_t)(gi * BG + b) * HSZ + jj * HS + c4 * 8) = v;
            }
            if (tid == 0)  // wave0's stores are in its vmcnt; release drains them
                __hip_atomic_fetch_add(mycnt, 1, __ATOMIC_RELEASE,
                                       __HIP_MEMORY_SCOPE_AGENT);
        }
    }
}

// out[b] = h_last[b,:] . Wout + bout
__global__ void out_kernel(const float* __restrict__ hlast,
                           const float* __restrict__ wout,
                           const float* __restrict__ bout,
                           float* __restrict__ out)
{
    const int b = blockIdx.x;
    const int l = threadIdx.x;
    float p = 0.f;
    for (int k = l; k < HSZ; k += 64)
        p += hlast[(size_t)b * HSZ + k] * wout[k];
    for (int off = 32; off > 0; off >>= 1)
        p += __shfl_down(p, off, 64);
    if (l == 0) out[b] = p + bout[0];
}

extern "C" void kernel_launch(void* const* d_in, const int* in_sizes, int n_in,
                              void* d_out, int out_size, void* d_ws, size_t ws_size,
                              hipStream_t stream) {
    const float* input_seq = (const float*)d_in[0];
    const float* Kin       = (const float*)d_in[1];
    const float* R         = (const float*)d_in[2];
    const float* bias      = (const float*)d_in[3];
    const float* Wout      = (const float*)d_in[4];
    const float* bout      = (const float*)d_in[5];
    float* out = (float*)d_out;

    char* ws = (char*)d_ws;
    unsigned short* wpack = (unsigned short*)(ws);                    // 2,359,296 B
    unsigned short* hbuf0 = (unsigned short*)(ws + 2359296);          //   262,144 B
    unsigned short* hbuf1 = (unsigned short*)(ws + 2359296 + 262144); //   262,144 B
    float* hlast          = (float*)(ws + 2359296 + 524288);          //   524,288 B
    int* cnt              = (int*)(ws + 2359296 + 524288 + 524288);   //     1,024 B

    zero_cnt<<<dim3(1), dim3(256), 0, stream>>>(cnt);
    pack_w<<<dim3(576), dim3(256), 0, stream>>>(R, Kin, wpack);
    lstm_persist<<<dim3(256), dim3(256), 0, stream>>>(
        wpack, input_seq, bias, hbuf0, hbuf1, hlast, cnt);
    out_kernel<<<dim3(256), dim3(64), 0, stream>>>(hlast, Wout, bout, out);
}

// Round 3
// 2349.473 us; speedup vs baseline: 1.8960x; 1.8960x over previous
//
#include <hip/hip_runtime.h>

// LSTM: B=256, T=512, I=64, H=512, G=4H=2048.
// gates = W @ [h; x], W = [R | kernel^T], K = 576.
// Persistent kernel: 128 WGs x 512 threads = 16 batch-groups x 8 WG each.
// W in VGPR/AGPR (144/lane), c in VGPRs. h exchanged through IF$-coherent
// relaxed atomic ops (no acquire/release fences -> no L2 wb/inv storms).
#define TSTEPS 512
#define BATCH  256
#define ISZ    64
#define HSZ    512
#define GSZ    2048
#define KCAT   576
#define NKT    18
#define BG     16

typedef __attribute__((ext_vector_type(8))) short short8;
typedef __attribute__((ext_vector_type(4))) float f32x4;

static __device__ __forceinline__ unsigned short f2bf(float f) {
    unsigned int u = __float_as_uint(f);
    return (unsigned short)((u + 0x7fffu + ((u >> 16) & 1u)) >> 16);  // RNE
}
static __device__ __forceinline__ float sig_(float x) {
    return 1.0f / (1.0f + __expf(-x));
}
static __device__ __forceinline__ float tanh_(float x) {
    float e = __expf(-2.0f * fabsf(x));
    float t = (1.0f - e) / (1.0f + e);
    return copysignf(t, x);
}
// Agent-coherent (per-op, no fence) accessors.
static __device__ __forceinline__ void st_agent_u16(unsigned short* p, unsigned short v) {
    __hip_atomic_store(p, v, __ATOMIC_RELAXED, __HIP_MEMORY_SCOPE_AGENT);
}
static __device__ __forceinline__ unsigned int ld_agent_u32(const unsigned int* p) {
    return __hip_atomic_load(p, __ATOMIC_RELAXED, __HIP_MEMORY_SCOPE_AGENT);
}

// Pack W = [R | kernel^T] (fp32) into bf16 MFMA A-fragment order.
// Frag t = ((jj*8 + m)*18 + kt)*64 + lane; row r = 16m + (lane&15);
// gate q = r&3; hco = r>>2; global row = q*512 + jj*32 + hco.
__global__ void pack_w(const float* __restrict__ R, const float* __restrict__ Kin,
                       unsigned short* __restrict__ wpack)
{
    const int t  = blockIdx.x * 256 + threadIdx.x;
    const int l  = t & 63;
    const int kt = (t >> 6) % NKT;
    const int m  = (t / (64 * NKT)) & 7;
    const int jj = t / (64 * NKT * 8);
    const int r   = 16 * m + (l & 15);
    const int q   = r & 3;
    const int hco = r >> 2;
    const int grow  = q * HSZ + jj * 32 + hco;
    const int kbase = kt * 32 + (l >> 4) * 8;
    unsigned int pk[4];
#pragma unroll
    for (int p = 0; p < 4; ++p) {
        const int k0 = kbase + 2 * p;
        const int k1 = k0 + 1;
        const float f0 = (k0 < HSZ) ? R[(size_t)grow * HSZ + k0]
                                    : Kin[(size_t)(k0 - HSZ) * GSZ + grow];
        const float f1 = (k1 < HSZ) ? R[(size_t)grow * HSZ + k1]
                                    : Kin[(size_t)(k1 - HSZ) * GSZ + grow];
        pk[p] = (unsigned)f2bf(f0) | ((unsigned)f2bf(f1) << 16);
    }
    uint4 v = make_uint4(pk[0], pk[1], pk[2], pk[3]);
    *reinterpret_cast<uint4*>(wpack + (size_t)t * 8) = v;
}

__global__ void zero_cnt(int* __restrict__ cnt) {
    cnt[threadIdx.x] = 0;
}

__global__ __launch_bounds__(512, 2) void lstm_persist(
    const unsigned short* __restrict__ wpack,
    const float* __restrict__ input_seq,
    const float* __restrict__ bias,
    unsigned short* __restrict__ hbuf0,
    unsigned short* __restrict__ hbuf1,
    float* __restrict__ hlast,
    int* __restrict__ cnt)
{
    __shared__ unsigned short lds_B[16][584];   // [batch][k], +8 pad
    const int tid = threadIdx.x;
    const int bid = blockIdx.x;
    // XCD swizzle: the 8 WGs of group gi share bid&7 -> same XCD (heuristic).
    const int gi = (bid & 7) + 8 * (bid >> 6);
    const int jw = (bid >> 3) & 7;

    const int w  = tid >> 6;
    const int l  = tid & 63;
    const int bb = l & 15;     // batch within group (D col)
    const int lg = l >> 4;
    const int jj = 2 * jw + (w >> 2);   // gate-slice (0..15)
    const int mw = w & 3;
    const int m0 = 2 * mw, m1 = 2 * mw + 1;

    // ---- one-time: W fragments into registers (144 VGPRs) ----
    short8 wA[NKT], wB[NKT];
#pragma unroll
    for (int kt = 0; kt < NKT; ++kt) {
        wA[kt] = *reinterpret_cast<const short8*>(
            wpack + (((size_t)(jj * 8 + m0) * NKT + kt) * 64 + l) * 8);
        wB[kt] = *reinterpret_cast<const short8*>(
            wpack + (((size_t)(jj * 8 + m1) * NKT + kt) * 64 + l) * 8);
    }
    const int hc0 = 4 * m0 + lg, hc1 = 4 * m1 + lg;
    const int gh0 = jj * 32 + hc0, gh1 = jj * 32 + hc1;
    float bs0[4], bs1[4];
#pragma unroll
    for (int qg = 0; qg < 4; ++qg) {
        bs0[qg] = bias[qg * HSZ + gh0];
        bs1[qg] = bias[qg * HSZ + gh1];
    }

    float c0 = 0.f, c1 = 0.f;

    // x prefetch: thread (xb, xck) of waves 0..3 owns 4 floats of batch xb's x_t
    const int xb = tid >> 4, xck = tid & 15;   // valid for tid < 256
    const float* xbase = input_seq + (size_t)(gi * BG + (xb & 15)) * (TSTEPS * ISZ) + xck * 4;
    float4 xr = *reinterpret_cast<const float4*>(xbase);
    int* const mycnt = cnt + gi * 32;   // 128B apart per group

    for (int s = 0; s < TSTEPS; ++s) {
        // ---- wait for h(s): each of 8 peer WGs incremented s times ----
        if (s > 0 && tid == 0) {
            while (ld_agent_u32((const unsigned int*)mycnt) < (unsigned)(8 * s)) { }
        }
        __syncthreads();   // A: h(s) visible; prev-step LDS reads done

        // ---- stage B = [h(s); x(s)] (waves 0..3) ----
        if (tid < 256) {
            // x part
            uint2 px;
            px.x = (unsigned)f2bf(xr.x) | ((unsigned)f2bf(xr.y) << 16);
            px.y = (unsigned)f2bf(xr.z) | ((unsigned)f2bf(xr.w) << 16);
            *reinterpret_cast<uint2*>(&lds_B[xb][HSZ + xck * 4]) = px;
            if (s + 1 < TSTEPS)
                xr = *reinterpret_cast<const float4*>(xbase + (size_t)(s + 1) * ISZ);
            // h part: 32 ushorts = 16 coherent dword loads
            if (s > 0) {
                const unsigned short* hr = (s & 1) ? hbuf1 : hbuf0;
                const unsigned int* src = reinterpret_cast<const unsigned int*>(
                    hr + (size_t)(gi * BG + xb) * HSZ + xck * 32);
                unsigned int hv[16];
#pragma unroll
                for (int i = 0; i < 16; ++i) hv[i] = ld_agent_u32(src + i);
                uint4* dst = reinterpret_cast<uint4*>(&lds_B[xb][xck * 32]);
#pragma unroll
                for (int i = 0; i < 4; ++i)
                    dst[i] = make_uint4(hv[4 * i], hv[4 * i + 1], hv[4 * i + 2], hv[4 * i + 3]);
            } else {
                uint4 z = make_uint4(0, 0, 0, 0);
                uint4* dst = reinterpret_cast<uint4*>(&lds_B[xb][xck * 32]);
                dst[0] = z; dst[1] = z; dst[2] = z; dst[3] = z;
            }
        }
        __syncthreads();   // B: staging complete

        f32x4 acc0 = {0.f, 0.f, 0.f, 0.f};
        f32x4 acc1 = {0.f, 0.f, 0.f, 0.f};
#pragma unroll
        for (int kt = 0; kt < NKT; ++kt) {
            const short8 bf = *reinterpret_cast<const short8*>(
                &lds_B[bb][kt * 32 + lg * 8]);
            acc0 = __builtin_amdgcn_mfma_f32_16x16x32_bf16(wA[kt], bf, acc0, 0, 0, 0);
            acc1 = __builtin_amdgcn_mfma_f32_16x16x32_bf16(wB[kt], bf, acc1, 0, 0, 0);
        }

        // ---- lane-local cell update ----
        const float fg0 = sig_(acc0[0] + bs0[0]);
        const float ig0 = sig_(acc0[1] + bs0[1]);
        const float cp0 = tanh_(acc0[2] + bs0[2]);
        const float og0 = sig_(acc0[3] + bs0[3]);
        c0 = fg0 * c0 + ig0 * cp0;
        const float h0 = og0 * tanh_(c0);
        const float fg1 = sig_(acc1[0] + bs1[0]);
        const float ig1 = sig_(acc1[1] + bs1[1]);
        const float cp1 = tanh_(acc1[2] + bs1[2]);
        const float og1 = sig_(acc1[3] + bs1[3]);
        c1 = fg1 * c1 + ig1 * cp1;
        const float h1 = og1 * tanh_(c1);

        if (s < TSTEPS - 1) {
            unsigned short* hw = (s & 1) ? hbuf0 : hbuf1;   // parity of s+1
            st_agent_u16(&hw[(size_t)(gi * BG + bb) * HSZ + gh0], f2bf(h0));
            st_agent_u16(&hw[(size_t)(gi * BG + bb) * HSZ + gh1], f2bf(h1));
            asm volatile("s_waitcnt vmcnt(0)" ::: "memory");  // store-ack (per wave)
            __syncthreads();   // D: all waves' h stores acked
            if (tid == 0)
                __hip_atomic_fetch_add(mycnt, 1, __ATOMIC_RELAXED,
                                       __HIP_MEMORY_SCOPE_AGENT);
        } else {
            hlast[(size_t)(gi * BG + bb) * HSZ + gh0] = h0;
            hlast[(size_t)(gi * BG + bb) * HSZ + gh1] = h1;
        }
    }
}

// out[b] = h_last[b,:] . Wout + bout
__global__ void out_kernel(const float* __restrict__ hlast,
                           const float* __restrict__ wout,
                           const float* __restrict__ bout,
                           float* __restrict__ out)
{
    const int b = blockIdx.x;
    const int l = threadIdx.x;
    float p = 0.f;
    for (int k = l; k < HSZ; k += 64)
        p += hlast[(size_t)b * HSZ + k] * wout[k];
    for (int off = 32; off > 0; off >>= 1)
        p += __shfl_down(p, off, 64);
    if (l == 0) out[b] = p + bout[0];
}

extern "C" void kernel_launch(void* const* d_in, const int* in_sizes, int n_in,
                              void* d_out, int out_size, void* d_ws, size_t ws_size,
                              hipStream_t stream) {
    const float* input_seq = (const float*)d_in[0];
    const float* Kin       = (const float*)d_in[1];
    const float* R         = (const float*)d_in[2];
    const float* bias      = (const float*)d_in[3];
    const float* Wout      = (const float*)d_in[4];
    const float* bout      = (const float*)d_in[5];
    float* out = (float*)d_out;

    char* ws = (char*)d_ws;
    unsigned short* wpack = (unsigned short*)(ws);                    // 2,359,296 B
    unsigned short* hbuf0 = (unsigned short*)(ws + 2359296);          //   262,144 B
    unsigned short* hbuf1 = (unsigned short*)(ws + 2359296 + 262144); //   262,144 B
    float* hlast          = (float*)(ws + 2359296 + 524288);          //   524,288 B
    int* cnt              = (int*)(ws + 2359296 + 524288 + 524288);   //     2,048 B

    zero_cnt<<<dim3(1), dim3(512), 0, stream>>>(cnt);
    pack_w<<<dim3(576), dim3(256), 0, stream>>>(R, Kin, wpack);
    lstm_persist<<<dim3(128), dim3(512), 0, stream>>>(
        wpack, input_seq, bias, hbuf0, hbuf1, hlast, cnt);
    out_kernel<<<dim3(256), dim3(64), 0, stream>>>(hlast, Wout, bout, out);
}